// Round 18
// baseline (229.744 us; speedup 1.0000x reference)
//
#include <hip/hip_runtime.h>
#include <math.h>

#define N_NODES 512
#define NE      4096
#define H       128
#define HH      1024
#define RBFK    64
#define KCAT    576   // 128 (ai) + 384 (eij) + 64 (rbf)
#define ALPHA   0.08838834764831845f

typedef __attribute__((ext_vector_type(8))) short bf16x8;
typedef __attribute__((ext_vector_type(4))) float f32x4;
typedef __attribute__((ext_vector_type(4))) short short4v;

__device__ __forceinline__ short f2bf(float x) {
    unsigned u = __builtin_bit_cast(unsigned, x);
    unsigned r = u + 0x7FFFu + ((u >> 16) & 1u);   // RNE
    return (short)(r >> 16);
}
__device__ __forceinline__ float bf2f(short s) {
    return __builtin_bit_cast(float, ((unsigned)(unsigned short)s) << 16);
}

__device__ __forceinline__ void gload16(const short* g, short* l) {
    __builtin_amdgcn_global_load_lds(
        (const __attribute__((address_space(1))) void*)g,
        (__attribute__((address_space(3))) void*)l, 16, 0, 0);
}

// ---------------- fused sort: extract + hist + scan + scatter + tgt-CSR ----------------
__global__ __launch_bounds__(512) void k_sort(
    const int* __restrict__ ei, const float* __restrict__ ew,
    int* __restrict__ srcS, int* __restrict__ tgtS, float* __restrict__ ewS,
    int* __restrict__ idxT,
    int* __restrict__ segStart, int* __restrict__ segStartT,
    int* __restrict__ nsegp, float* __restrict__ cvec)
{
    __shared__ int sSrc[NE];      // 16 KB
    __shared__ int sTgt[NE];      // 16 KB
    __shared__ int sTgtS[NE];     // 16 KB (tgt at sorted position)
    __shared__ int hS[N_NODES], hT[N_NODES], sS[N_NODES], sT[N_NODES];
    __shared__ int flag;
    int t = threadIdx.x;
    if (t == 0) {
        int any = 0;
        for (int i = 1; i < 128; i += 2) any |= ei[i];
        flag = (any == 0);
    }
    hS[t] = 0; hT[t] = 0;
    if (t < H) cvec[t] = 0.0f;
    __syncthreads();
    int is64 = flag;
    for (int e = t; e < NE; e += 512) {
        int s = is64 ? ei[2 * e]          : ei[e];
        int g = is64 ? ei[2 * NE + 2 * e] : ei[NE + e];
        sSrc[e] = s; sTgt[e] = g;
        atomicAdd(&hS[s], 1);
        atomicAdd(&hT[g], 1);
    }
    __syncthreads();
    int cs = hS[t], ct = hT[t];
    sS[t] = cs; sT[t] = ct;
    __syncthreads();
    for (int off = 1; off < N_NODES; off <<= 1) {
        int a = (t >= off) ? sS[t - off] : 0;
        int b = (t >= off) ? sT[t - off] : 0;
        __syncthreads();
        sS[t] += a; sT[t] += b;
        __syncthreads();
    }
    segStart[t + 1]  = sS[t];
    segStartT[t + 1] = sT[t];
    if (t == 0) { segStart[0] = 0; segStartT[0] = 0; }
    int exS = sS[t] - cs, exT = sT[t] - ct;
    __syncthreads();
    hS[t] = exS;              // reuse as src-cursor
    hT[t] = exT;              // reuse as tgt-cursor
    sS[t] = (cs > 0) ? 1 : 0; // reuse for nseg reduction
    __syncthreads();
    for (int off = 256; off > 0; off >>= 1) {
        if (t < off) sS[t] += sS[t + off];
        __syncthreads();
    }
    if (t == 0) nsegp[0] = sS[0];
    __syncthreads();
    // scatter by src
    for (int e = t; e < NE; e += 512) {
        int s = sSrc[e], g = sTgt[e];
        int p = atomicAdd(&hS[s], 1);
        srcS[p] = s; tgtS[p] = g; ewS[p] = ew[e];
        sTgtS[p] = g;
    }
    __syncthreads();
    // tgt CSR over sorted positions
    for (int p = t; p < NE; p += 512) {
        int q = atomicAdd(&hT[sTgtS[p]], 1);
        idxT[q] = p;
    }
}

// ---------------- fused prep ----------------
#define RA 524288      // NE*H edge features
#define RB 589824      // BcatT 576*1024
#define RBZ 65536      // BcatT zero rows 576..639
#define RW 262144      // WqkT 2048*128
#define RCW 2048       // cwq+cwk colsums
#define RD 131072      // olT
#define RE 32768       // liT+ljT
#define RG 65536       // embB 512*128
#define RF 4096        // cvec partial sums
#define RTOT (RA+RB+RBZ+RW+RCW+RD+RE+RG+RF)

__global__ void k_prep_all(
    const float* __restrict__ atom_embs, const float* __restrict__ pos,
    const int* __restrict__ srcS, const int* __restrict__ tgtS, const float* __restrict__ ewS,
    const float* __restrict__ Wq, const float* __restrict__ Wk, const float* __restrict__ Wv,
    const float* __restrict__ li_w, const float* __restrict__ lj_w,
    const float* __restrict__ el_w, const float* __restrict__ rl_w,
    const float* __restrict__ ol_w, const float* __restrict__ el_b, const float* __restrict__ rl_b,
    short* __restrict__ Acat, short* __restrict__ ajB, short* __restrict__ BcatT,
    short* __restrict__ WqkT, float* __restrict__ cwq, float* __restrict__ cwk,
    short* __restrict__ olT, short* __restrict__ liT, short* __restrict__ ljT,
    short* __restrict__ embB, float* __restrict__ cvec)
{
    int idx = blockIdx.x * blockDim.x + threadIdx.x;
    if (idx < RA) {
        int p = idx >> 7, h = idx & 127;
        int s = srcS[p], t = tgtS[p];
        float ew = ewS[p];
        Acat[(size_t)p * KCAT + h] = f2bf(atom_embs[t * H + h] + ew);
        ajB[idx] = f2bf(atom_embs[s * H + h] + ew);
        if (h < RBFK) {
            float dx = pos[t * 3 + 0] - pos[s * 3 + 0];
            float dy = pos[t * 3 + 1] - pos[s * 3 + 1];
            float dz = pos[t * 3 + 2] - pos[s * 3 + 2];
            float d = sqrtf(dx * dx + dy * dy + dz * dz);
            float x = d * 0.1f;
            float cut = 0.0f;
            if (x < 1.0f) {
                float x3 = x * x * x, x4 = x3 * x, x5 = x4 * x;
                cut = 1.0f - 6.0f * x5 + 15.0f * x4 - 10.0f * x3;
            }
            float ck = 1.0f + (float)h * (-0.015872295239210119f);
            float tt = expf(-d) - ck;
            Acat[(size_t)p * KCAT + 512 + h] = f2bf(cut * expf(-1024.0929857f * tt * tt));
        }
        return;
    }
    idx -= RA;
    if (idx < RB) {                       // BcatT rows: [Wv; el_w; rl_w]
        int k = idx >> 10, n = idx & 1023;
        float v = (k < 128) ? Wv[k * HH + n]
                : (k < 512) ? el_w[(k - 128) * HH + n]
                            : rl_w[(k - 512) * HH + n];
        BcatT[idx] = f2bf(v);
        return;
    }
    idx -= RB;
    if (idx < RBZ) { BcatT[RB + idx] = 0; return; }
    idx -= RBZ;
    if (idx < RW) {                       // WqkT [2048 x 128]
        int n = idx >> 7, k = idx & 127;
        float v = (n < 1024) ? Wq[k * HH + n] : Wk[k * HH + (n - 1024)];
        WqkT[idx] = f2bf(v);
        return;
    }
    idx -= RW;
    if (idx < RCW) {                      // cwq/cwk column sums
        int which = idx >> 10, j = idx & 1023;
        const float* W = which ? Wk : Wq;
        float s = 0.0f;
        for (int k = 0; k < H; k++) s += W[k * HH + j];
        (which ? cwk : cwq)[j] = s;
        return;
    }
    idx -= RCW;
    if (idx < RD) {                       // olT [128 x 1024]
        int h = idx >> 10, n = idx & 1023;
        olT[idx] = f2bf(ol_w[n * H + h]);
        return;
    }
    idx -= RD;
    if (idx < RE) {                       // liT / ljT
        int which = idx >> 14, r = idx & 16383;
        int n = r >> 7, k = r & 127;
        (which ? ljT : liT)[r] = f2bf((which ? lj_w : li_w)[k * H + n]);
        return;
    }
    idx -= RE;
    if (idx < RG) { embB[idx] = f2bf(atom_embs[idx]); return; }
    idx -= RG;
    if (idx < RF) {                       // cvec partials
        int h = idx & 127, chunk = idx >> 7;
        float acc = 0.0f;
        int n0 = chunk * 32;
        for (int n = n0; n < n0 + 32; n++)
            acc += (el_b[n] + rl_b[n]) * ol_w[n * H + h];
        atomicAdd(&cvec[h], acc);
    }
}

// ---------------- shared MFMA NT GEMM body (256 threads) ----------------
// out_mode: 0 = f32 (offset zoff_pitch), 1 = bf16, 3 = bf16 transposed
__device__ __forceinline__ void gemm_body(
    short* As, short* Bs,
    const short* __restrict__ A, int lda,
    const short* __restrict__ B, int ldb,
    void* __restrict__ Cp, int ldc,
    int kbeg, int kend, float alpha, const float* __restrict__ bias,
    long zoff_pitch, int out_mode, int row0, int col0)
{
    const int tid = threadIdx.x;
    const int wave = tid >> 6, lane = tid & 63;

    f32x4 acc[4][4];
#pragma unroll
    for (int i = 0; i < 4; i++)
#pragma unroll
        for (int j = 0; j < 4; j++) acc[i][j] = (f32x4){0.f, 0.f, 0.f, 0.f};

    const int m0 = (wave >> 1) * 64, n0 = (wave & 1) * 64;
    const int lr = lane >> 3;
    const int lc = (lane & 7) * 8;
    const int cl = lane & 15, quad = lane >> 4;

    for (int k0 = kbeg; k0 < kend; k0 += 64) {
#pragma unroll
        for (int i = 0; i < 4; i++) {
            int r = wave * 32 + i * 8;
            gload16(A + (size_t)(row0 + r + lr) * lda + k0 + lc, As + r * 64);
            gload16(B + (size_t)(col0 + r + lr) * ldb + k0 + lc, Bs + r * 64);
        }
        __syncthreads();
#pragma unroll
        for (int kk = 0; kk < 64; kk += 32) {
            bf16x8 af[4], bf[4];
            int ko = kk + quad * 8;
#pragma unroll
            for (int i = 0; i < 4; i++)
                af[i] = *(const bf16x8*)(As + (m0 + i * 16 + cl) * 64 + ko);
#pragma unroll
            for (int j = 0; j < 4; j++)
                bf[j] = *(const bf16x8*)(Bs + (n0 + j * 16 + cl) * 64 + ko);
#pragma unroll
            for (int i = 0; i < 4; i++)
#pragma unroll
                for (int j = 0; j < 4; j++)
                    acc[i][j] = __builtin_amdgcn_mfma_f32_16x16x32_bf16(af[i], bf[j], acc[i][j], 0, 0, 0);
        }
        __syncthreads();
    }

    if (out_mode == 1) {
        short* C = (short*)Cp;
#pragma unroll
        for (int i = 0; i < 4; i++)
#pragma unroll
            for (int j = 0; j < 4; j++) {
                int cc = col0 + n0 + j * 16 + cl;
                float bv = bias ? bias[cc] : 0.0f;
#pragma unroll
                for (int reg = 0; reg < 4; reg++) {
                    int rr = row0 + m0 + i * 16 + quad * 4 + reg;
                    C[(size_t)rr * ldc + cc] = f2bf(acc[i][j][reg] * alpha + bv);
                }
            }
    } else if (out_mode == 3) {
        short* C = (short*)Cp;
#pragma unroll
        for (int i = 0; i < 4; i++)
#pragma unroll
            for (int j = 0; j < 4; j++) {
                int cc = col0 + n0 + j * 16 + cl;
                int rr = row0 + m0 + i * 16 + quad * 4;
                short4v pack;
#pragma unroll
                for (int reg = 0; reg < 4; reg++) pack[reg] = f2bf(acc[i][j][reg] * alpha);
                *(short4v*)(C + (size_t)cc * ldc + rr) = pack;
            }
    } else {
        float* C = (float*)Cp + zoff_pitch;
#pragma unroll
        for (int i = 0; i < 4; i++)
#pragma unroll
            for (int j = 0; j < 4; j++) {
                int cc = col0 + n0 + j * 16 + cl;
#pragma unroll
                for (int reg = 0; reg < 4; reg++) {
                    int rr = row0 + m0 + i * 16 + quad * 4 + reg;
                    C[(size_t)rr * ldc + cc] = acc[i][j][reg] * alpha;
                }
            }
    }
}

__global__ __launch_bounds__(256) void k_gemm(
    const short* __restrict__ A, int lda,
    const short* __restrict__ B, int ldb,
    void* __restrict__ Cp, int ldc,
    int K, float alpha, const float* __restrict__ bias,
    long split_pitch, int out_mode)
{
    __shared__ __align__(16) short As[128 * 64];
    __shared__ __align__(16) short Bs[128 * 64];
    int kchunk = K / gridDim.z;
    gemm_body(As, Bs, A, lda, B, ldb, Cp, ldc,
              kchunk * blockIdx.z, kchunk * (blockIdx.z + 1), alpha, bias,
              (long)blockIdx.z * split_pitch, out_mode,
              blockIdx.y * 128, blockIdx.x * 128);
}

// ---------------- edgefeat body (device) ----------------
__device__ __forceinline__ void edgefeat_body(
    short* As, short* Bs, int row0,
    const short* __restrict__ Acat_in, const short* __restrict__ ajB,
    const short* __restrict__ liT, const short* __restrict__ ljT,
    const float* __restrict__ li_b, const float* __restrict__ lj_b,
    short* __restrict__ Acat)
{
    const int tid = threadIdx.x;
    const int wave = tid >> 6, lane = tid & 63;
    const int cl = lane & 15, quad = lane >> 4;
    const int m0 = (wave >> 1) * 64, n0 = (wave & 1) * 64;
    const int sr = lane >> 4, sc = (lane & 15) * 8;

    f32x4 ai_acc[4][4], aj_acc[4][4];
#pragma unroll
    for (int i = 0; i < 4; i++)
#pragma unroll
        for (int j = 0; j < 4; j++) {
            ai_acc[i][j] = (f32x4){0.f, 0.f, 0.f, 0.f};
            aj_acc[i][j] = (f32x4){0.f, 0.f, 0.f, 0.f};
        }

#pragma unroll
    for (int i = 0; i < 8; i++) {
        int r = wave * 32 + i * 4;
        gload16(Acat_in + (size_t)(row0 + r + sr) * KCAT + sc, As + r * 128);
        gload16(liT + (r + sr) * 128 + sc, Bs + r * 128);
    }
    __syncthreads();
#pragma unroll
    for (int kk = 0; kk < 128; kk += 32) {
        bf16x8 af[4], bf[4];
        int ko = kk + quad * 8;
#pragma unroll
        for (int i = 0; i < 4; i++) af[i] = *(const bf16x8*)(As + (m0 + i * 16 + cl) * 128 + ko);
#pragma unroll
        for (int j = 0; j < 4; j++) bf[j] = *(const bf16x8*)(Bs + (n0 + j * 16 + cl) * 128 + ko);
#pragma unroll
        for (int i = 0; i < 4; i++)
#pragma unroll
            for (int j = 0; j < 4; j++)
                ai_acc[i][j] = __builtin_amdgcn_mfma_f32_16x16x32_bf16(af[i], bf[j], ai_acc[i][j], 0, 0, 0);
    }
    __syncthreads();
#pragma unroll
    for (int i = 0; i < 8; i++) {
        int r = wave * 32 + i * 4;
        gload16(ajB + (size_t)(row0 + r + sr) * 128 + sc, As + r * 128);
        gload16(ljT + (r + sr) * 128 + sc, Bs + r * 128);
    }
    __syncthreads();
#pragma unroll
    for (int kk = 0; kk < 128; kk += 32) {
        bf16x8 af[4], bf[4];
        int ko = kk + quad * 8;
#pragma unroll
        for (int i = 0; i < 4; i++) af[i] = *(const bf16x8*)(As + (m0 + i * 16 + cl) * 128 + ko);
#pragma unroll
        for (int j = 0; j < 4; j++) bf[j] = *(const bf16x8*)(Bs + (n0 + j * 16 + cl) * 128 + ko);
#pragma unroll
        for (int i = 0; i < 4; i++)
#pragma unroll
            for (int j = 0; j < 4; j++)
                aj_acc[i][j] = __builtin_amdgcn_mfma_f32_16x16x32_bf16(af[i], bf[j], aj_acc[i][j], 0, 0, 0);
    }
#pragma unroll
    for (int i = 0; i < 4; i++)
#pragma unroll
        for (int j = 0; j < 4; j++) {
            int cc = n0 + j * 16 + cl;
            float bi = li_b[cc], bj = lj_b[cc];
#pragma unroll
            for (int reg = 0; reg < 4; reg++) {
                int rr = row0 + m0 + i * 16 + quad * 4 + reg;
                float hv = ai_acc[i][j][reg] + bi;
                float gv = aj_acc[i][j][reg] + bj;
                short* rowp = Acat + (size_t)rr * KCAT;
                rowp[128 + cc] = f2bf(hv + gv);
                rowp[256 + cc] = f2bf(hv - gv);
                rowp[384 + cc] = f2bf(hv * gv);
            }
        }
}

// ---------------- D4: edgefeat(32) + QK'(64) + W2T(5) ----------------
__global__ __launch_bounds__(256) void k_big(
    const short* __restrict__ Acat_in, const short* __restrict__ ajB,
    const short* __restrict__ liT, const short* __restrict__ ljT,
    const float* __restrict__ li_b, const float* __restrict__ lj_b,
    short* __restrict__ Acat,
    const short* __restrict__ embB, const short* __restrict__ WqkT,
    short* __restrict__ QKB,
    const short* __restrict__ olT, const short* __restrict__ BcatT,
    short* __restrict__ W2T)
{
    __shared__ __align__(16) char smem[65536];
    if (blockIdx.x < 32) {
        edgefeat_body((short*)smem, (short*)(smem + 32768), blockIdx.x * 128,
                      Acat_in, ajB, liT, ljT, li_b, lj_b, Acat);
    } else if (blockIdx.x < 96) {
        int id = blockIdx.x - 32;
        gemm_body((short*)smem, (short*)(smem + 16384),
                  embB, H, WqkT, H, QKB, 2048, 0, H, 1.0f, nullptr, 0, 1,
                  (id >> 4) * 128, (id & 15) * 128);
    } else {
        int id = blockIdx.x - 96;
        gemm_body((short*)smem, (short*)(smem + 16384),
                  olT, HH, BcatT, HH, W2T, 640, 0, HH, 1.0f, nullptr, 0, 1,
                  0, id * 128);
    }
}

// ---------------- D5: Z(16) + GT(32) + wave-parallel p/q/s (16) ----------------
__global__ __launch_bounds__(256) void k_zr(
    const short* __restrict__ QKB,
    const float* __restrict__ cwq, const float* __restrict__ cwk,
    const short* __restrict__ Acat, const short* __restrict__ W2T,
    short* __restrict__ GT,
    float* __restrict__ Z, float* __restrict__ pv, float* __restrict__ qv,
    float* __restrict__ sv)
{
    __shared__ __align__(16) char smem[32768];
    if (blockIdx.x < 16) {
        gemm_body((short*)smem, (short*)(smem + 16384),
                  QKB, 2048, QKB + 1024, 2048, Z, N_NODES, 0, HH, ALPHA, nullptr, 0, 0,
                  (blockIdx.x >> 2) * 128, (blockIdx.x & 3) * 128);
    } else if (blockIdx.x < 48) {
        int id = blockIdx.x - 16;
        gemm_body((short*)smem, (short*)(smem + 16384),
                  Acat, KCAT, W2T, 640, GT, NE, 0, KCAT, 1.0f, nullptr, 0, 3,
                  id * 128, 0);
    } else {
        int b = blockIdx.x - 48;
        int t = threadIdx.x;
        int wave = t >> 6, lane = t & 63;
        if (b == 0 && wave == 0) {
            float a = 0.0f;
            for (int j = lane; j < HH; j += 64) a += cwq[j] * cwk[j];
            for (int off = 32; off > 0; off >>= 1) a += __shfl_down(a, off);
            if (lane == 0) sv[0] = a;
        }
        for (int ni = 0; ni < 8; ni++) {
            int n = b * 32 + wave * 8 + ni;
            const short* qr = QKB + (size_t)n * 2048;
            float pa = 0.0f, qa = 0.0f;
            int j0 = lane * 16;
#pragma unroll
            for (int j = 0; j < 16; j++) {
                pa += bf2f(qr[j0 + j]) * cwk[j0 + j];
                qa += bf2f(qr[1024 + j0 + j]) * cwq[j0 + j];
            }
            for (int off = 32; off > 0; off >>= 1) {
                pa += __shfl_down(pa, off);
                qa += __shfl_down(qa, off);
            }
            if (lane == 0) { pv[n] = pa; qv[n] = qa; }
        }
    }
}

// ---------------- denom (512 threads): rDen[r][n] = 1/sum_{c in seg n} exp(l[r,c]) ----------------
// l[r,c] = (Z[tr,tc] + α·er·q[tc]) + ec·β,  β = α·(p_tr + er·s)
__global__ __launch_bounds__(512) void k_denom(
    const float* __restrict__ Z, const float* __restrict__ pv,
    const float* __restrict__ qv, const float* __restrict__ sv,
    const int* __restrict__ tgtS, const float* __restrict__ ewS,
    const int* __restrict__ segStart, float* __restrict__ rDen)
{
    __shared__ float row[NE];        // 16 KB
    __shared__ float zq[N_NODES];    // 2 KB
    const int r = blockIdx.x, t = threadIdx.x;
    const int tr = tgtS[r];
    const float er = ewS[r];
    const float aer = ALPHA * er;
    for (int i = t; i < N_NODES; i += 512)
        zq[i] = Z[(size_t)tr * N_NODES + i] + aer * qv[i];
    __syncthreads();
    const float beta = ALPHA * (pv[tr] + er * sv[0]);
    for (int c = t; c < NE; c += 512)
        row[c] = __expf(zq[tgtS[c]] + ewS[c] * beta);
    __syncthreads();
    float* rd = rDen + (size_t)r * N_NODES;
    if (t < N_NODES) {
        int a = segStart[t], b = segStart[t + 1];
        float s = 0.0f;
        for (int p = a; p < b; p++) s += row[p];
        rd[t] = (s > 0.0f) ? 1.0f / s : 0.0f;
    }
}

// ---------------- Pagg (barrier-free) ----------------
__global__ __launch_bounds__(256) void k_pagg2(
    const float* __restrict__ Z, const float* __restrict__ pv,
    const float* __restrict__ qv, const float* __restrict__ sv,
    const float* __restrict__ rDen,
    const int* __restrict__ tgtS, const float* __restrict__ ewS,
    const int* __restrict__ srcS, const int* __restrict__ segStartT,
    const int* __restrict__ idxT, short* __restrict__ PaggB)
{
    __shared__ float zrow[N_NODES];   // 2 KB
    __shared__ float aq[N_NODES];     // 2 KB (alpha * q)
    __shared__ float erL[32];
    __shared__ int   eL[32];
    const int n = blockIdx.y;
    const int c0 = blockIdx.x * 1024;
    const int t = threadIdx.x;
    for (int i = t; i < N_NODES; i += 256) {
        zrow[i] = Z[(size_t)n * N_NODES + i];
        aq[i]   = ALPHA * qv[i];
    }
    __syncthreads();
    const float p_n = pv[n];
    const float s = sv[0];
    float A4[4], cB4[4];
    int sc4[4];
#pragma unroll
    for (int q = 0; q < 4; q++) {
        int c = c0 + t + q * 256;
        int tc = tgtS[c]; float ec = ewS[c];
        A4[q]  = zrow[tc] + (ALPHA * ec) * p_n;
        cB4[q] = aq[tc] + (ALPHA * ec) * s;
        sc4[q] = srcS[c];
    }
    float acc[4] = {0.f, 0.f, 0.f, 0.f};
    const int a = segStartT[n], b = segStartT[n + 1];
    for (int ch = a; ch < b; ch += 32) {
        int ne = b - ch; if (ne > 32) ne = 32;
        __syncthreads();
        if (t < ne) { int e = idxT[ch + t]; eL[t] = e; erL[t] = ewS[e]; }
        __syncthreads();
        for (int k = 0; k < ne; k++) {
            const float er = erL[k];
            const float* rde = rDen + (size_t)eL[k] * N_NODES;
#pragma unroll
            for (int q = 0; q < 4; q++)
                acc[q] += __expf(A4[q] + er * cB4[q]) * rde[sc4[q]];
        }
    }
    short* pr = PaggB + (size_t)n * NE + c0;
#pragma unroll
    for (int q = 0; q < 4; q++)
        pr[t + q * 256] = f2bf(acc[q]);
}

// ---------------- head: sum 8 agg partials + LN + FFN + LN ----------------
__global__ __launch_bounds__(128) void k_head(
    const float* __restrict__ aggP, const int* __restrict__ segStartT,
    const int* __restrict__ nsegp,
    const float* __restrict__ cvec, const float* __restrict__ ol_b,
    const float* __restrict__ ln_g, const float* __restrict__ ln_b,
    const float* __restrict__ f1_w, const float* __restrict__ f1_b,
    const float* __restrict__ f2_w, const float* __restrict__ f2_b,
    const float* __restrict__ f3_w, const float* __restrict__ f3_b,
    float* __restrict__ out)
{
    __shared__ float x[H];
    __shared__ float red[H];
    int t = threadIdx.x, row = blockIdx.x;
    int cnt = segStartT[row + 1] - segStartT[row];
    float v = (float)cnt * (ol_b[t] + (float)nsegp[0] * cvec[t]);
    const float* ap = aggP + (size_t)row * H + t;
#pragma unroll
    for (int z = 0; z < 8; z++) v += ap[(size_t)z * N_NODES * H];
    red[t] = v; __syncthreads();
    for (int s = 64; s > 0; s >>= 1) { if (t < s) red[t] += red[t + s]; __syncthreads(); }
    float mu = red[0] * (1.0f / H); __syncthreads();
    float dv = v - mu;
    red[t] = dv * dv; __syncthreads();
    for (int s = 64; s > 0; s >>= 1) { if (t < s) red[t] += red[t + s]; __syncthreads(); }
    float var = red[0] * (1.0f / H); __syncthreads();
    x[t] = dv * rsqrtf(var + 1e-5f) * ln_g[t] + ln_b[t];
    __syncthreads();
    const float* Ws[3] = { f1_w, f2_w, f3_w };
    const float* Bb[3] = { f1_b, f2_b, f3_b };
    for (int l = 0; l < 3; l++) {
        float acc = Bb[l][t];
        const float* Wl = Ws[l];
        for (int k = 0; k < H; k++) acc = fmaf(x[k], Wl[k * H + t], acc);
        float o = fmaxf(acc, 0.0f) + log1pf(expf(-fabsf(acc)));
        __syncthreads();
        x[t] = o;
        __syncthreads();
    }
    float xv = x[t];
    red[t] = xv; __syncthreads();
    for (int s = 64; s > 0; s >>= 1) { if (t < s) red[t] += red[t + s]; __syncthreads(); }
    mu = red[0] * (1.0f / H); __syncthreads();
    float dv2 = xv - mu;
    red[t] = dv2 * dv2; __syncthreads();
    for (int s = 64; s > 0; s >>= 1) { if (t < s) red[t] += red[t + s]; __syncthreads(); }
    var = red[0] * (1.0f / H);
    out[row * H + t] = dv2 * rsqrtf(var + 1e-5f) * ln_g[t] + ln_b[t];
}

// ---------------- launch ----------------

extern "C" void kernel_launch(void* const* d_in, const int* in_sizes, int n_in,
                              void* d_out, int out_size, void* d_ws, size_t ws_size,
                              hipStream_t stream) {
    const float* atom_embs   = (const float*)d_in[0];
    const float* pos         = (const float*)d_in[1];
    const float* edge_weight = (const float*)d_in[2];
    const int*   edge_idx    = (const int*)d_in[3];
    const float* Wq   = (const float*)d_in[4];
    const float* Wk   = (const float*)d_in[5];
    const float* Wv   = (const float*)d_in[6];
    const float* li_w = (const float*)d_in[7];
    const float* li_b = (const float*)d_in[8];
    const float* lj_w = (const float*)d_in[9];
    const float* lj_b = (const float*)d_in[10];
    const float* el_w = (const float*)d_in[11];
    const float* el_b = (const float*)d_in[12];
    const float* rl_w = (const float*)d_in[13];
    const float* rl_b = (const float*)d_in[14];
    const float* ol_w = (const float*)d_in[15];
    const float* ol_b = (const float*)d_in[16];
    const float* ln_g = (const float*)d_in[17];
    const float* ln_b = (const float*)d_in[18];
    const float* f1_w = (const float*)d_in[19];
    const float* f1_b = (const float*)d_in[20];
    const float* f2_w = (const float*)d_in[21];
    const float* f2_b = (const float*)d_in[22];
    const float* f3_w = (const float*)d_in[23];
    const float* f3_b = (const float*)d_in[24];
    float* out = (float*)d_out;

    char* w = (char*)d_ws;
    size_t off = 0;
    auto alloc = [&](size_t bytes) -> void* {
        void* p = w + off;
        off += (bytes + 255) & ~(size_t)255;
        return p;
    };
    int*   srcS      = (int*)alloc(NE * 4);
    int*   tgtS      = (int*)alloc(NE * 4);
    float* ewS       = (float*)alloc(NE * 4);
    int*   segStart  = (int*)alloc((N_NODES + 1) * 4);
    int*   segStartT = (int*)alloc((N_NODES + 1) * 4);
    int*   idxT      = (int*)alloc(NE * 4);
    int*   nsegp     = (int*)alloc(4);
    short* Acat   = (short*)alloc((size_t)NE * KCAT * 2);
    short* ajB    = (short*)alloc((size_t)NE * H * 2);
    short* BcatT  = (short*)alloc((size_t)640 * HH * 2);
    short* WqkT   = (short*)alloc((size_t)2048 * H * 2);
    float* cwq    = (float*)alloc(HH * 4);
    float* cwk    = (float*)alloc(HH * 4);
    short* olT    = (short*)alloc((size_t)H * HH * 2);
    short* liT    = (short*)alloc((size_t)H * H * 2);
    short* ljT    = (short*)alloc((size_t)H * H * 2);
    short* embB   = (short*)alloc((size_t)N_NODES * H * 2);
    float* cvec   = (float*)alloc(H * 4);
    short* W2T    = (short*)alloc((size_t)H * 640 * 2);
    short* QKB    = (short*)alloc((size_t)N_NODES * 2048 * 2);
    float* Z      = (float*)alloc((size_t)N_NODES * N_NODES * 4);
    float* pv     = (float*)alloc(N_NODES * 4);
    float* qv     = (float*)alloc(N_NODES * 4);
    float* sv     = (float*)alloc(4);
    short* GT     = (short*)alloc((size_t)H * NE * 2);
    float* rDen   = (float*)alloc((size_t)NE * N_NODES * 4);
    short* PaggB  = (short*)alloc((size_t)N_NODES * NE * 2);
    float* aggP   = (float*)alloc((size_t)8 * N_NODES * H * 4);

    // D1: fused sort (extract + hist + scan + scatter + tgt-CSR)
    k_sort<<<1, 512, 0, stream>>>(edge_idx, edge_weight, srcS, tgtS, ewS, idxT,
                                  segStart, segStartT, nsegp, cvec);
    // D2: prep
    k_prep_all<<<(RTOT + 255) / 256, 256, 0, stream>>>(
        atom_embs, pos, srcS, tgtS, ewS,
        Wq, Wk, Wv, li_w, lj_w, el_w, rl_w, ol_w, el_b, rl_b,
        Acat, ajB, BcatT, WqkT, cwq, cwk, olT, liT, ljT, embB, cvec);
    // D3: edgefeat + QK' + W2T
    k_big<<<101, 256, 0, stream>>>(Acat, ajB, liT, ljT, li_b, lj_b, Acat,
                                   embB, WqkT, QKB, olT, BcatT, W2T);
    // D4: Z + GT + wave-parallel p/q/s
    k_zr<<<64, 256, 0, stream>>>(QKB, cwq, cwk, Acat, W2T, GT, Z, pv, qv, sv);
    // D5: denominators (512 threads)
    k_denom<<<NE, 512, 0, stream>>>(Z, pv, qv, sv, tgtS, ewS, segStart, rDen);
    // D6: Pagg
    {
        dim3 g(4, N_NODES);
        k_pagg2<<<g, 256, 0, stream>>>(Z, pv, qv, sv, rDen, tgtS, ewS, srcS,
                                       segStartT, idxT, PaggB);
    }
    // D7: agg = Pagg @ G : split-K=8
    {
        dim3 g(1, N_NODES / 128, 8);
        k_gemm<<<g, 256, 0, stream>>>(PaggB, NE, GT, NE, aggP, H, NE, 1.0f, nullptr,
                                      (long)N_NODES * H, 0);
    }
    // D8: head
    k_head<<<N_NODES, 128, 0, stream>>>(aggP, segStartT, nsegp, cvec, ol_b,
                                        ln_g, ln_b, f1_w, f1_b, f2_w, f2_b, f3_w, f3_b, out);
}

// Round 20
// 224.405 us; speedup vs baseline: 1.0238x; 1.0238x over previous
//
#include <hip/hip_runtime.h>
#include <math.h>

#define N_NODES 512
#define NE      4096
#define H       128
#define HH      1024
#define RBFK    64
#define KCAT    576   // 128 (ai) + 384 (eij) + 64 (rbf)
#define ALPHA   0.08838834764831845f

typedef __attribute__((ext_vector_type(8))) short bf16x8;
typedef __attribute__((ext_vector_type(4))) float f32x4;
typedef __attribute__((ext_vector_type(4))) short short4v;

__device__ __forceinline__ short f2bf(float x) {
    unsigned u = __builtin_bit_cast(unsigned, x);
    unsigned r = u + 0x7FFFu + ((u >> 16) & 1u);   // RNE
    return (short)(r >> 16);
}
__device__ __forceinline__ float bf2f(short s) {
    return __builtin_bit_cast(float, ((unsigned)(unsigned short)s) << 16);
}

__device__ __forceinline__ void gload16(const short* g, short* l) {
    __builtin_amdgcn_global_load_lds(
        (const __attribute__((address_space(1))) void*)g,
        (__attribute__((address_space(3))) void*)l, 16, 0, 0);
}

// ---------------- sort pipeline ----------------

__global__ __launch_bounds__(512) void k_scan(
    const int* __restrict__ ei,
    int* __restrict__ srcG, int* __restrict__ tgtG,
    int* __restrict__ segStart, int* __restrict__ segStartT,
    int* __restrict__ cursorS, int* __restrict__ cursorT, int* __restrict__ nsegp,
    float* __restrict__ cvec)
{
    __shared__ int hS[N_NODES], hT[N_NODES], sS[N_NODES], sT[N_NODES];
    __shared__ int flag;
    int t = threadIdx.x;
    if (t == 0) {
        int any = 0;
        for (int i = 1; i < 128; i += 2) any |= ei[i];
        flag = (any == 0);
    }
    hS[t] = 0; hT[t] = 0;
    if (t < H) cvec[t] = 0.0f;
    __syncthreads();
    int is64 = flag;
    for (int e = t; e < NE; e += 512) {
        int s = is64 ? ei[2 * e]          : ei[e];
        int g = is64 ? ei[2 * NE + 2 * e] : ei[NE + e];
        srcG[e] = s; tgtG[e] = g;
        atomicAdd(&hS[s], 1);
        atomicAdd(&hT[g], 1);
    }
    __syncthreads();
    int cs = hS[t], ct = hT[t];
    sS[t] = cs; sT[t] = ct;
    __syncthreads();
    for (int off = 1; off < N_NODES; off <<= 1) {
        int a = (t >= off) ? sS[t - off] : 0;
        int b = (t >= off) ? sT[t - off] : 0;
        __syncthreads();
        sS[t] += a; sT[t] += b;
        __syncthreads();
    }
    segStart[t + 1]  = sS[t];
    segStartT[t + 1] = sT[t];
    if (t == 0) { segStart[0] = 0; segStartT[0] = 0; }
    cursorS[t] = sS[t] - cs;
    cursorT[t] = sT[t] - ct;
    hS[t] = (cs > 0) ? 1 : 0;
    __syncthreads();
    for (int off = 256; off > 0; off >>= 1) {
        if (t < off) hS[t] += hS[t + off];
        __syncthreads();
    }
    if (t == 0) nsegp[0] = hS[0];
}

__global__ void k_scatter(const int* __restrict__ src, const int* __restrict__ tgt,
                          const float* __restrict__ ew,
                          int* __restrict__ cursorS, int* __restrict__ cursorT,
                          int* __restrict__ srcS, int* __restrict__ tgtS,
                          float* __restrict__ ewS, int* __restrict__ idxT) {
    int e = blockIdx.x * blockDim.x + threadIdx.x;
    if (e < NE) {
        int s = src[e], g = tgt[e];
        int p = atomicAdd(&cursorS[s], 1);
        srcS[p] = s; tgtS[p] = g; ewS[p] = ew[e];
        int q = atomicAdd(&cursorT[g], 1);
        idxT[q] = p;
    }
}

// ---------------- fused prep ----------------
#define RA 524288      // NE*H edge features
#define RB 589824      // BcatT 576*1024
#define RBZ 65536      // BcatT zero rows 576..639
#define RW 262144      // WqkT 2048*128
#define RCW 2048       // cwq+cwk colsums
#define RD 131072      // olT
#define RE 32768       // liT+ljT
#define RG 65536       // embB 512*128
#define RF 4096        // cvec partial sums
#define RTOT (RA+RB+RBZ+RW+RCW+RD+RE+RG+RF)

__global__ void k_prep_all(
    const float* __restrict__ atom_embs, const float* __restrict__ pos,
    const int* __restrict__ srcS, const int* __restrict__ tgtS, const float* __restrict__ ewS,
    const float* __restrict__ Wq, const float* __restrict__ Wk, const float* __restrict__ Wv,
    const float* __restrict__ li_w, const float* __restrict__ lj_w,
    const float* __restrict__ el_w, const float* __restrict__ rl_w,
    const float* __restrict__ ol_w, const float* __restrict__ el_b, const float* __restrict__ rl_b,
    short* __restrict__ Acat, short* __restrict__ ajB, short* __restrict__ BcatT,
    short* __restrict__ WqkT, float* __restrict__ cwq, float* __restrict__ cwk,
    short* __restrict__ olT, short* __restrict__ liT, short* __restrict__ ljT,
    short* __restrict__ embB, float* __restrict__ cvec)
{
    int idx = blockIdx.x * blockDim.x + threadIdx.x;
    if (idx < RA) {
        int p = idx >> 7, h = idx & 127;
        int s = srcS[p], t = tgtS[p];
        float ew = ewS[p];
        Acat[(size_t)p * KCAT + h] = f2bf(atom_embs[t * H + h] + ew);
        ajB[idx] = f2bf(atom_embs[s * H + h] + ew);
        if (h < RBFK) {
            float dx = pos[t * 3 + 0] - pos[s * 3 + 0];
            float dy = pos[t * 3 + 1] - pos[s * 3 + 1];
            float dz = pos[t * 3 + 2] - pos[s * 3 + 2];
            float d = sqrtf(dx * dx + dy * dy + dz * dz);
            float x = d * 0.1f;
            float cut = 0.0f;
            if (x < 1.0f) {
                float x3 = x * x * x, x4 = x3 * x, x5 = x4 * x;
                cut = 1.0f - 6.0f * x5 + 15.0f * x4 - 10.0f * x3;
            }
            float ck = 1.0f + (float)h * (-0.015872295239210119f);
            float tt = expf(-d) - ck;
            Acat[(size_t)p * KCAT + 512 + h] = f2bf(cut * expf(-1024.0929857f * tt * tt));
        }
        return;
    }
    idx -= RA;
    if (idx < RB) {                       // BcatT rows: [Wv; el_w; rl_w]
        int k = idx >> 10, n = idx & 1023;
        float v = (k < 128) ? Wv[k * HH + n]
                : (k < 512) ? el_w[(k - 128) * HH + n]
                            : rl_w[(k - 512) * HH + n];
        BcatT[idx] = f2bf(v);
        return;
    }
    idx -= RB;
    if (idx < RBZ) { BcatT[RB + idx] = 0; return; }
    idx -= RBZ;
    if (idx < RW) {                       // WqkT [2048 x 128]
        int n = idx >> 7, k = idx & 127;
        float v = (n < 1024) ? Wq[k * HH + n] : Wk[k * HH + (n - 1024)];
        WqkT[idx] = f2bf(v);
        return;
    }
    idx -= RW;
    if (idx < RCW) {                      // cwq/cwk column sums
        int which = idx >> 10, j = idx & 1023;
        const float* W = which ? Wk : Wq;
        float s = 0.0f;
        for (int k = 0; k < H; k++) s += W[k * HH + j];
        (which ? cwk : cwq)[j] = s;
        return;
    }
    idx -= RCW;
    if (idx < RD) {                       // olT [128 x 1024]
        int h = idx >> 10, n = idx & 1023;
        olT[idx] = f2bf(ol_w[n * H + h]);
        return;
    }
    idx -= RD;
    if (idx < RE) {                       // liT / ljT
        int which = idx >> 14, r = idx & 16383;
        int n = r >> 7, k = r & 127;
        (which ? ljT : liT)[r] = f2bf((which ? lj_w : li_w)[k * H + n]);
        return;
    }
    idx -= RE;
    if (idx < RG) { embB[idx] = f2bf(atom_embs[idx]); return; }
    idx -= RG;
    if (idx < RF) {                       // cvec partials
        int h = idx & 127, chunk = idx >> 7;
        float acc = 0.0f;
        int n0 = chunk * 32;
        for (int n = n0; n < n0 + 32; n++)
            acc += (el_b[n] + rl_b[n]) * ol_w[n * H + h];
        atomicAdd(&cvec[h], acc);
    }
}

// ---------------- shared MFMA NT GEMM body (256 threads) ----------------
// out_mode: 0 = f32 (offset zoff_pitch), 1 = bf16, 3 = bf16 transposed
__device__ __forceinline__ void gemm_body(
    short* As, short* Bs,
    const short* __restrict__ A, int lda,
    const short* __restrict__ B, int ldb,
    void* __restrict__ Cp, int ldc,
    int kbeg, int kend, float alpha, const float* __restrict__ bias,
    long zoff_pitch, int out_mode, int row0, int col0)
{
    const int tid = threadIdx.x;
    const int wave = tid >> 6, lane = tid & 63;

    f32x4 acc[4][4];
#pragma unroll
    for (int i = 0; i < 4; i++)
#pragma unroll
        for (int j = 0; j < 4; j++) acc[i][j] = (f32x4){0.f, 0.f, 0.f, 0.f};

    const int m0 = (wave >> 1) * 64, n0 = (wave & 1) * 64;
    const int lr = lane >> 3;
    const int lc = (lane & 7) * 8;
    const int cl = lane & 15, quad = lane >> 4;

    for (int k0 = kbeg; k0 < kend; k0 += 64) {
#pragma unroll
        for (int i = 0; i < 4; i++) {
            int r = wave * 32 + i * 8;
            gload16(A + (size_t)(row0 + r + lr) * lda + k0 + lc, As + r * 64);
            gload16(B + (size_t)(col0 + r + lr) * ldb + k0 + lc, Bs + r * 64);
        }
        __syncthreads();
#pragma unroll
        for (int kk = 0; kk < 64; kk += 32) {
            bf16x8 af[4], bf[4];
            int ko = kk + quad * 8;
#pragma unroll
            for (int i = 0; i < 4; i++)
                af[i] = *(const bf16x8*)(As + (m0 + i * 16 + cl) * 64 + ko);
#pragma unroll
            for (int j = 0; j < 4; j++)
                bf[j] = *(const bf16x8*)(Bs + (n0 + j * 16 + cl) * 64 + ko);
#pragma unroll
            for (int i = 0; i < 4; i++)
#pragma unroll
                for (int j = 0; j < 4; j++)
                    acc[i][j] = __builtin_amdgcn_mfma_f32_16x16x32_bf16(af[i], bf[j], acc[i][j], 0, 0, 0);
        }
        __syncthreads();
    }

    if (out_mode == 1) {
        short* C = (short*)Cp;
#pragma unroll
        for (int i = 0; i < 4; i++)
#pragma unroll
            for (int j = 0; j < 4; j++) {
                int cc = col0 + n0 + j * 16 + cl;
                float bv = bias ? bias[cc] : 0.0f;
#pragma unroll
                for (int reg = 0; reg < 4; reg++) {
                    int rr = row0 + m0 + i * 16 + quad * 4 + reg;
                    C[(size_t)rr * ldc + cc] = f2bf(acc[i][j][reg] * alpha + bv);
                }
            }
    } else if (out_mode == 3) {
        short* C = (short*)Cp;
#pragma unroll
        for (int i = 0; i < 4; i++)
#pragma unroll
            for (int j = 0; j < 4; j++) {
                int cc = col0 + n0 + j * 16 + cl;
                int rr = row0 + m0 + i * 16 + quad * 4;
                short4v pack;
#pragma unroll
                for (int reg = 0; reg < 4; reg++) pack[reg] = f2bf(acc[i][j][reg] * alpha);
                *(short4v*)(C + (size_t)cc * ldc + rr) = pack;
            }
    } else {
        float* C = (float*)Cp + zoff_pitch;
#pragma unroll
        for (int i = 0; i < 4; i++)
#pragma unroll
            for (int j = 0; j < 4; j++) {
                int cc = col0 + n0 + j * 16 + cl;
#pragma unroll
                for (int reg = 0; reg < 4; reg++) {
                    int rr = row0 + m0 + i * 16 + quad * 4 + reg;
                    C[(size_t)rr * ldc + cc] = acc[i][j][reg] * alpha;
                }
            }
    }
}

__global__ __launch_bounds__(256) void k_gemm(
    const short* __restrict__ A, int lda,
    const short* __restrict__ B, int ldb,
    void* __restrict__ Cp, int ldc,
    int K, float alpha, const float* __restrict__ bias,
    long split_pitch, int out_mode)
{
    __shared__ __align__(16) short As[128 * 64];
    __shared__ __align__(16) short Bs[128 * 64];
    int kchunk = K / gridDim.z;
    gemm_body(As, Bs, A, lda, B, ldb, Cp, ldc,
              kchunk * blockIdx.z, kchunk * (blockIdx.z + 1), alpha, bias,
              (long)blockIdx.z * split_pitch, out_mode,
              blockIdx.y * 128, blockIdx.x * 128);
}

// ---------------- edgefeat body (device) ----------------
__device__ __forceinline__ void edgefeat_body(
    short* As, short* Bs, int row0,
    const short* __restrict__ Acat_in, const short* __restrict__ ajB,
    const short* __restrict__ liT, const short* __restrict__ ljT,
    const float* __restrict__ li_b, const float* __restrict__ lj_b,
    short* __restrict__ Acat)
{
    const int tid = threadIdx.x;
    const int wave = tid >> 6, lane = tid & 63;
    const int cl = lane & 15, quad = lane >> 4;
    const int m0 = (wave >> 1) * 64, n0 = (wave & 1) * 64;
    const int sr = lane >> 4, sc = (lane & 15) * 8;

    f32x4 ai_acc[4][4], aj_acc[4][4];
#pragma unroll
    for (int i = 0; i < 4; i++)
#pragma unroll
        for (int j = 0; j < 4; j++) {
            ai_acc[i][j] = (f32x4){0.f, 0.f, 0.f, 0.f};
            aj_acc[i][j] = (f32x4){0.f, 0.f, 0.f, 0.f};
        }

#pragma unroll
    for (int i = 0; i < 8; i++) {
        int r = wave * 32 + i * 4;
        gload16(Acat_in + (size_t)(row0 + r + sr) * KCAT + sc, As + r * 128);
        gload16(liT + (r + sr) * 128 + sc, Bs + r * 128);
    }
    __syncthreads();
#pragma unroll
    for (int kk = 0; kk < 128; kk += 32) {
        bf16x8 af[4], bf[4];
        int ko = kk + quad * 8;
#pragma unroll
        for (int i = 0; i < 4; i++) af[i] = *(const bf16x8*)(As + (m0 + i * 16 + cl) * 128 + ko);
#pragma unroll
        for (int j = 0; j < 4; j++) bf[j] = *(const bf16x8*)(Bs + (n0 + j * 16 + cl) * 128 + ko);
#pragma unroll
        for (int i = 0; i < 4; i++)
#pragma unroll
            for (int j = 0; j < 4; j++)
                ai_acc[i][j] = __builtin_amdgcn_mfma_f32_16x16x32_bf16(af[i], bf[j], ai_acc[i][j], 0, 0, 0);
    }
    __syncthreads();
#pragma unroll
    for (int i = 0; i < 8; i++) {
        int r = wave * 32 + i * 4;
        gload16(ajB + (size_t)(row0 + r + sr) * 128 + sc, As + r * 128);
        gload16(ljT + (r + sr) * 128 + sc, Bs + r * 128);
    }
    __syncthreads();
#pragma unroll
    for (int kk = 0; kk < 128; kk += 32) {
        bf16x8 af[4], bf[4];
        int ko = kk + quad * 8;
#pragma unroll
        for (int i = 0; i < 4; i++) af[i] = *(const bf16x8*)(As + (m0 + i * 16 + cl) * 128 + ko);
#pragma unroll
        for (int j = 0; j < 4; j++) bf[j] = *(const bf16x8*)(Bs + (n0 + j * 16 + cl) * 128 + ko);
#pragma unroll
        for (int i = 0; i < 4; i++)
#pragma unroll
            for (int j = 0; j < 4; j++)
                aj_acc[i][j] = __builtin_amdgcn_mfma_f32_16x16x32_bf16(af[i], bf[j], aj_acc[i][j], 0, 0, 0);
    }
#pragma unroll
    for (int i = 0; i < 4; i++)
#pragma unroll
        for (int j = 0; j < 4; j++) {
            int cc = n0 + j * 16 + cl;
            float bi = li_b[cc], bj = lj_b[cc];
#pragma unroll
            for (int reg = 0; reg < 4; reg++) {
                int rr = row0 + m0 + i * 16 + quad * 4 + reg;
                float hv = ai_acc[i][j][reg] + bi;
                float gv = aj_acc[i][j][reg] + bj;
                short* rowp = Acat + (size_t)rr * KCAT;
                rowp[128 + cc] = f2bf(hv + gv);
                rowp[256 + cc] = f2bf(hv - gv);
                rowp[384 + cc] = f2bf(hv * gv);
            }
        }
}

// ---------------- D4: edgefeat(32) + QK'(64) + W2T(5) ----------------
__global__ __launch_bounds__(256) void k_big(
    const short* __restrict__ Acat_in, const short* __restrict__ ajB,
    const short* __restrict__ liT, const short* __restrict__ ljT,
    const float* __restrict__ li_b, const float* __restrict__ lj_b,
    short* __restrict__ Acat,
    const short* __restrict__ embB, const short* __restrict__ WqkT,
    short* __restrict__ QKB,
    const short* __restrict__ olT, const short* __restrict__ BcatT,
    short* __restrict__ W2T)
{
    __shared__ __align__(16) char smem[65536];
    if (blockIdx.x < 32) {
        edgefeat_body((short*)smem, (short*)(smem + 32768), blockIdx.x * 128,
                      Acat_in, ajB, liT, ljT, li_b, lj_b, Acat);
    } else if (blockIdx.x < 96) {
        int id = blockIdx.x - 32;
        gemm_body((short*)smem, (short*)(smem + 16384),
                  embB, H, WqkT, H, QKB, 2048, 0, H, 1.0f, nullptr, 0, 1,
                  (id >> 4) * 128, (id & 15) * 128);
    } else {
        int id = blockIdx.x - 96;
        gemm_body((short*)smem, (short*)(smem + 16384),
                  olT, HH, BcatT, HH, W2T, 640, 0, HH, 1.0f, nullptr, 0, 1,
                  0, id * 128);
    }
}

// ---------------- D5: Z(16) + GT(32) + wave-parallel p/q/s (16) ----------------
__global__ __launch_bounds__(256) void k_zr(
    const short* __restrict__ QKB,
    const float* __restrict__ cwq, const float* __restrict__ cwk,
    const short* __restrict__ Acat, const short* __restrict__ W2T,
    short* __restrict__ GT,
    float* __restrict__ Z, float* __restrict__ pv, float* __restrict__ qv,
    float* __restrict__ sv)
{
    __shared__ __align__(16) char smem[32768];
    if (blockIdx.x < 16) {
        gemm_body((short*)smem, (short*)(smem + 16384),
                  QKB, 2048, QKB + 1024, 2048, Z, N_NODES, 0, HH, ALPHA, nullptr, 0, 0,
                  (blockIdx.x >> 2) * 128, (blockIdx.x & 3) * 128);
    } else if (blockIdx.x < 48) {
        int id = blockIdx.x - 16;
        gemm_body((short*)smem, (short*)(smem + 16384),
                  Acat, KCAT, W2T, 640, GT, NE, 0, KCAT, 1.0f, nullptr, 0, 3,
                  id * 128, 0);
    } else {
        int b = blockIdx.x - 48;
        int t = threadIdx.x;
        int wave = t >> 6, lane = t & 63;
        if (b == 0 && wave == 0) {
            float a = 0.0f;
            for (int j = lane; j < HH; j += 64) a += cwq[j] * cwk[j];
            for (int off = 32; off > 0; off >>= 1) a += __shfl_down(a, off);
            if (lane == 0) sv[0] = a;
        }
        for (int ni = 0; ni < 8; ni++) {
            int n = b * 32 + wave * 8 + ni;
            const short* qr = QKB + (size_t)n * 2048;
            float pa = 0.0f, qa = 0.0f;
            int j0 = lane * 16;
#pragma unroll
            for (int j = 0; j < 16; j++) {
                pa += bf2f(qr[j0 + j]) * cwk[j0 + j];
                qa += bf2f(qr[1024 + j0 + j]) * cwq[j0 + j];
            }
            for (int off = 32; off > 0; off >>= 1) {
                pa += __shfl_down(pa, off);
                qa += __shfl_down(qa, off);
            }
            if (lane == 0) { pv[n] = pa; qv[n] = qa; }
        }
    }
}

// ---------------- denom (512 threads): rDen[r][n] = 1/sum_{c in seg n} exp(l[r,c]) ----------------
// l[r,c] = (Z[tr,tc] + α·er·q[tc]) + ec·β,  β = α·(p_tr + er·s)
__global__ __launch_bounds__(512) void k_denom(
    const float* __restrict__ Z, const float* __restrict__ pv,
    const float* __restrict__ qv, const float* __restrict__ sv,
    const int* __restrict__ tgtS, const float* __restrict__ ewS,
    const int* __restrict__ segStart, float* __restrict__ rDen)
{
    __shared__ float row[NE];        // 16 KB
    __shared__ float zq[N_NODES];    // 2 KB
    const int r = blockIdx.x, t = threadIdx.x;
    const int tr = tgtS[r];
    const float er = ewS[r];
    const float aer = ALPHA * er;
    for (int i = t; i < N_NODES; i += 512)
        zq[i] = Z[(size_t)tr * N_NODES + i] + aer * qv[i];
    __syncthreads();
    const float beta = ALPHA * (pv[tr] + er * sv[0]);
    for (int c = t; c < NE; c += 512)
        row[c] = __expf(zq[tgtS[c]] + ewS[c] * beta);
    __syncthreads();
    float* rd = rDen + (size_t)r * N_NODES;
    if (t < N_NODES) {
        int a = segStart[t], b = segStart[t + 1];
        float s = 0.0f;
        for (int p = a; p < b; p++) s += row[p];
        rd[t] = (s > 0.0f) ? 1.0f / s : 0.0f;
    }
}

// ---------------- Pagg (barrier-free) ----------------
__global__ __launch_bounds__(256) void k_pagg2(
    const float* __restrict__ Z, const float* __restrict__ pv,
    const float* __restrict__ qv, const float* __restrict__ sv,
    const float* __restrict__ rDen,
    const int* __restrict__ tgtS, const float* __restrict__ ewS,
    const int* __restrict__ srcS, const int* __restrict__ segStartT,
    const int* __restrict__ idxT, short* __restrict__ PaggB)
{
    __shared__ float zrow[N_NODES];   // 2 KB
    __shared__ float aq[N_NODES];     // 2 KB (alpha * q)
    __shared__ float erL[32];
    __shared__ int   eL[32];
    const int n = blockIdx.y;
    const int c0 = blockIdx.x * 1024;
    const int t = threadIdx.x;
    for (int i = t; i < N_NODES; i += 256) {
        zrow[i] = Z[(size_t)n * N_NODES + i];
        aq[i]   = ALPHA * qv[i];
    }
    __syncthreads();
    const float p_n = pv[n];
    const float s = sv[0];
    float A4[4], cB4[4];
    int sc4[4];
#pragma unroll
    for (int q = 0; q < 4; q++) {
        int c = c0 + t + q * 256;
        int tc = tgtS[c]; float ec = ewS[c];
        A4[q]  = zrow[tc] + (ALPHA * ec) * p_n;
        cB4[q] = aq[tc] + (ALPHA * ec) * s;
        sc4[q] = srcS[c];
    }
    float acc[4] = {0.f, 0.f, 0.f, 0.f};
    const int a = segStartT[n], b = segStartT[n + 1];
    for (int ch = a; ch < b; ch += 32) {
        int ne = b - ch; if (ne > 32) ne = 32;
        __syncthreads();
        if (t < ne) { int e = idxT[ch + t]; eL[t] = e; erL[t] = ewS[e]; }
        __syncthreads();
        for (int k = 0; k < ne; k++) {
            const float er = erL[k];
            const float* rde = rDen + (size_t)eL[k] * N_NODES;
#pragma unroll
            for (int q = 0; q < 4; q++)
                acc[q] += __expf(A4[q] + er * cB4[q]) * rde[sc4[q]];
        }
    }
    short* pr = PaggB + (size_t)n * NE + c0;
#pragma unroll
    for (int q = 0; q < 4; q++)
        pr[t + q * 256] = f2bf(acc[q]);
}

// ---------------- head: sum 8 agg partials + LN + FFN + LN ----------------
__global__ __launch_bounds__(128) void k_head(
    const float* __restrict__ aggP, const int* __restrict__ segStartT,
    const int* __restrict__ nsegp,
    const float* __restrict__ cvec, const float* __restrict__ ol_b,
    const float* __restrict__ ln_g, const float* __restrict__ ln_b,
    const float* __restrict__ f1_w, const float* __restrict__ f1_b,
    const float* __restrict__ f2_w, const float* __restrict__ f2_b,
    const float* __restrict__ f3_w, const float* __restrict__ f3_b,
    float* __restrict__ out)
{
    __shared__ float x[H];
    __shared__ float red[H];
    int t = threadIdx.x, row = blockIdx.x;
    int cnt = segStartT[row + 1] - segStartT[row];
    float v = (float)cnt * (ol_b[t] + (float)nsegp[0] * cvec[t]);
    const float* ap = aggP + (size_t)row * H + t;
#pragma unroll
    for (int z = 0; z < 8; z++) v += ap[(size_t)z * N_NODES * H];
    red[t] = v; __syncthreads();
    for (int s = 64; s > 0; s >>= 1) { if (t < s) red[t] += red[t + s]; __syncthreads(); }
    float mu = red[0] * (1.0f / H); __syncthreads();
    float dv = v - mu;
    red[t] = dv * dv; __syncthreads();
    for (int s = 64; s > 0; s >>= 1) { if (t < s) red[t] += red[t + s]; __syncthreads(); }
    float var = red[0] * (1.0f / H); __syncthreads();
    x[t] = dv * rsqrtf(var + 1e-5f) * ln_g[t] + ln_b[t];
    __syncthreads();
    const float* Ws[3] = { f1_w, f2_w, f3_w };
    const float* Bb[3] = { f1_b, f2_b, f3_b };
    for (int l = 0; l < 3; l++) {
        float acc = Bb[l][t];
        const float* Wl = Ws[l];
        for (int k = 0; k < H; k++) acc = fmaf(x[k], Wl[k * H + t], acc);
        float o = fmaxf(acc, 0.0f) + log1pf(expf(-fabsf(acc)));
        __syncthreads();
        x[t] = o;
        __syncthreads();
    }
    float xv = x[t];
    red[t] = xv; __syncthreads();
    for (int s = 64; s > 0; s >>= 1) { if (t < s) red[t] += red[t + s]; __syncthreads(); }
    mu = red[0] * (1.0f / H); __syncthreads();
    float dv2 = xv - mu;
    red[t] = dv2 * dv2; __syncthreads();
    for (int s = 64; s > 0; s >>= 1) { if (t < s) red[t] += red[t + s]; __syncthreads(); }
    var = red[0] * (1.0f / H);
    out[row * H + t] = dv2 * rsqrtf(var + 1e-5f) * ln_g[t] + ln_b[t];
}

// ---------------- launch ----------------

extern "C" void kernel_launch(void* const* d_in, const int* in_sizes, int n_in,
                              void* d_out, int out_size, void* d_ws, size_t ws_size,
                              hipStream_t stream) {
    const float* atom_embs   = (const float*)d_in[0];
    const float* pos         = (const float*)d_in[1];
    const float* edge_weight = (const float*)d_in[2];
    const int*   edge_idx    = (const int*)d_in[3];
    const float* Wq   = (const float*)d_in[4];
    const float* Wk   = (const float*)d_in[5];
    const float* Wv   = (const float*)d_in[6];
    const float* li_w = (const float*)d_in[7];
    const float* li_b = (const float*)d_in[8];
    const float* lj_w = (const float*)d_in[9];
    const float* lj_b = (const float*)d_in[10];
    const float* el_w = (const float*)d_in[11];
    const float* el_b = (const float*)d_in[12];
    const float* rl_w = (const float*)d_in[13];
    const float* rl_b = (const float*)d_in[14];
    const float* ol_w = (const float*)d_in[15];
    const float* ol_b = (const float*)d_in[16];
    const float* ln_g = (const float*)d_in[17];
    const float* ln_b = (const float*)d_in[18];
    const float* f1_w = (const float*)d_in[19];
    const float* f1_b = (const float*)d_in[20];
    const float* f2_w = (const float*)d_in[21];
    const float* f2_b = (const float*)d_in[22];
    const float* f3_w = (const float*)d_in[23];
    const float* f3_b = (const float*)d_in[24];
    float* out = (float*)d_out;

    char* w = (char*)d_ws;
    size_t off = 0;
    auto alloc = [&](size_t bytes) -> void* {
        void* p = w + off;
        off += (bytes + 255) & ~(size_t)255;
        return p;
    };
    int*   src       = (int*)alloc(NE * 4);
    int*   tgt       = (int*)alloc(NE * 4);
    int*   srcS      = (int*)alloc(NE * 4);
    int*   tgtS      = (int*)alloc(NE * 4);
    float* ewS       = (float*)alloc(NE * 4);
    int*   segStart  = (int*)alloc((N_NODES + 1) * 4);
    int*   segStartT = (int*)alloc((N_NODES + 1) * 4);
    int*   cursorS   = (int*)alloc(N_NODES * 4);
    int*   cursorT   = (int*)alloc(N_NODES * 4);
    int*   idxT      = (int*)alloc(NE * 4);
    int*   nsegp     = (int*)alloc(4);
    short* Acat   = (short*)alloc((size_t)NE * KCAT * 2);
    short* ajB    = (short*)alloc((size_t)NE * H * 2);
    short* BcatT  = (short*)alloc((size_t)640 * HH * 2);
    short* WqkT   = (short*)alloc((size_t)2048 * H * 2);
    float* cwq    = (float*)alloc(HH * 4);
    float* cwk    = (float*)alloc(HH * 4);
    short* olT    = (short*)alloc((size_t)H * HH * 2);
    short* liT    = (short*)alloc((size_t)H * H * 2);
    short* ljT    = (short*)alloc((size_t)H * H * 2);
    short* embB   = (short*)alloc((size_t)N_NODES * H * 2);
    float* cvec   = (float*)alloc(H * 4);
    short* W2T    = (short*)alloc((size_t)H * 640 * 2);
    short* QKB    = (short*)alloc((size_t)N_NODES * 2048 * 2);
    float* Z      = (float*)alloc((size_t)N_NODES * N_NODES * 4);
    float* pv     = (float*)alloc(N_NODES * 4);
    float* qv     = (float*)alloc(N_NODES * 4);
    float* sv     = (float*)alloc(4);
    short* GT     = (short*)alloc((size_t)H * NE * 2);
    float* rDen   = (float*)alloc((size_t)NE * N_NODES * 4);
    short* PaggB  = (short*)alloc((size_t)N_NODES * NE * 2);
    float* aggP   = (float*)alloc((size_t)8 * N_NODES * H * 4);

    k_scan<<<1, 512, 0, stream>>>(edge_idx, src, tgt, segStart, segStartT,
                                  cursorS, cursorT, nsegp, cvec);
    k_scatter<<<NE / 256, 256, 0, stream>>>(src, tgt, edge_weight, cursorS, cursorT,
                                            srcS, tgtS, ewS, idxT);
    k_prep_all<<<(RTOT + 255) / 256, 256, 0, stream>>>(
        atom_embs, pos, srcS, tgtS, ewS,
        Wq, Wk, Wv, li_w, lj_w, el_w, rl_w, ol_w, el_b, rl_b,
        Acat, ajB, BcatT, WqkT, cwq, cwk, olT, liT, ljT, embB, cvec);

    // D4: edgefeat + QK' + W2T
    k_big<<<101, 256, 0, stream>>>(Acat, ajB, liT, ljT, li_b, lj_b, Acat,
                                   embB, WqkT, QKB, olT, BcatT, W2T);
    // D5: Z + GT + wave-parallel p/q/s
    k_zr<<<64, 256, 0, stream>>>(QKB, cwq, cwk, Acat, W2T, GT, Z, pv, qv, sv);
    // D6: denominators (512 threads)
    k_denom<<<NE, 512, 0, stream>>>(Z, pv, qv, sv, tgtS, ewS, segStart, rDen);
    // Pagg
    {
        dim3 g(4, N_NODES);
        k_pagg2<<<g, 256, 0, stream>>>(Z, pv, qv, sv, rDen, tgtS, ewS, srcS,
                                       segStartT, idxT, PaggB);
    }
    // agg = Pagg @ G : split-K=8
    {
        dim3 g(1, N_NODES / 128, 8);
        k_gemm<<<g, 256, 0, stream>>>(PaggB, NE, GT, NE, aggP, H, NE, 1.0f, nullptr,
                                      (long)N_NODES * H, 0);
    }
    k_head<<<N_NODES, 128, 0, stream>>>(aggP, segStartT, nsegp, cvec, ol_b,
                                        ln_g, ln_b, f1_w, f1_b, f2_w, f2_b, f3_w, f3_b, out);
}